// Round 1
// baseline (1872.002 us; speedup 1.0000x reference)
//
#include <hip/hip_runtime.h>
#include <hip/hip_bf16.h>
#include <math.h>

#define NFLOWS 5
#define DIMF 64
#define NHID 128
#define HID 8192
#define BATCHN 4096

typedef unsigned int u32;

__device__ __forceinline__ float bflo(u32 u){ return __uint_as_float(u << 16); }
__device__ __forceinline__ float bfhi(u32 u){ return __uint_as_float(u & 0xffff0000u); }

__device__ __forceinline__ float softplus_f(float z){
  return fmaxf(z, 0.f) + log1pf(__expf(-fabsf(z)));
}

// ---------------- prep1: wn1 (bf16) + g1 ----------------
// one 64-lane wave per row of W1 (5*8192 rows), lane = input col j (0..63)
__global__ __launch_bounds__(256) void prep1_kernel(
    const float* __restrict__ W1, const float* __restrict__ d1,
    __hip_bfloat16* __restrict__ wn1b, float* __restrict__ g1)
{
  int w = threadIdx.x >> 6;
  int lane = threadIdx.x & 63;
  int R = blockIdx.x * 4 + w;            // 0 .. 5*8192-1
  int rl = R & (HID - 1);
  int blk = rl >> 7;                     // dim index of this hidden row
  float Wv = W1[(size_t)R * DIMF + lane];
  float wv;
  if (lane == blk)      wv = __expf(Wv);   // diagonal block
  else if (lane < blk)  wv = Wv;           // strictly lower block
  else                  wv = 0.f;          // upper -> masked
  float sq = wv * wv;
  #pragma unroll
  for (int m = 1; m < 64; m <<= 1) sq += __shfl_xor(sq, m, 64);
  float d1v = d1[R];
  float sc = __expf(d1v) * rsqrtf(sq);
  wn1b[(size_t)R * DIMF + lane] = __float2bfloat16(wv * sc);
  if (lane == blk) g1[R] = d1v + Wv - 0.5f * __logf(sq);
}

// ---------------- prep2: wn2 (bf16) + c + cmax ----------------
// one 256-thread block per (flow f, out-row i); row has 8192 elements
__global__ __launch_bounds__(256) void prep2_kernel(
    const float* __restrict__ W2, const float* __restrict__ d2,
    const float* __restrict__ g1,
    __hip_bfloat16* __restrict__ wn2b, float* __restrict__ cvec,
    float* __restrict__ cmax)
{
  __shared__ float red[256];
  int f = blockIdx.x >> 6;
  int i = blockIdx.x & 63;
  int tid = threadIdx.x;
  const float* Wrow = W2 + ((size_t)(f * DIMF + i)) * HID;
  float d2v = d2[f * DIMF + i];
  float part = 0.f;
  for (int k = tid; k < HID; k += 256) {
    float Wv = Wrow[k];
    int kb = k >> 7;
    float wv = (kb == i) ? __expf(Wv) : ((kb < i) ? Wv : 0.f);
    part += wv * wv;
  }
  red[tid] = part; __syncthreads();
  for (int s = 128; s > 0; s >>= 1) {
    if (tid < s) red[tid] += red[tid + s];
    __syncthreads();
  }
  float wsn = red[0];
  __syncthreads();
  float ls = __logf(wsn);
  float sc = __expf(d2v) * rsqrtf(wsn);
  float lmax = -1e30f;
  for (int k = tid; k < HID; k += 256) {
    float Wv = Wrow[k];
    int kb = k >> 7;
    float wv = (kb == i) ? __expf(Wv) : ((kb < i) ? Wv : 0.f);
    wn2b[((size_t)(f * DIMF + i)) * HID + k] = __float2bfloat16(wv * sc);
    if (kb == i) {
      float cv = g1[f * HID + k] + d2v + Wv - 0.5f * ls;   // g1+g2 combined
      cvec[f * HID + k] = cv;
      lmax = fmaxf(lmax, cv);
    }
  }
  red[tid] = lmax; __syncthreads();
  for (int s = 128; s > 0; s >>= 1) {
    if (tid < s) red[tid] = fmaxf(red[tid], red[tid + s]);
    __syncthreads();
  }
  if (tid == 0) cmax[f * DIMF + i] = red[0];
}

// ---------------- main fused kernel: all 5 flows ----------------
// 256 blocks x 256 threads; block owns 16 batch rows; 4 waves split the
// 64 hidden blocks (128 wide). x stays in LDS across flows.
__global__ __launch_bounds__(256) void bnaf_main_kernel(
    const float* __restrict__ x_in,
    const float* __restrict__ b1, const float* __restrict__ b2,
    const float* __restrict__ gates,
    const __hip_bfloat16* __restrict__ wn1b,
    const __hip_bfloat16* __restrict__ wn2b,
    const float* __restrict__ cvec, const float* __restrict__ cmax,
    float* __restrict__ out)
{
  __shared__ float xs[16][64];
  __shared__ __attribute__((aligned(16))) float ts[4][16][132]; // pad 132: 2-way banks on GEMM2 reads
  __shared__ __attribute__((aligned(16))) float yp[4][16][64];
  __shared__ float ldp[4][16];
  __shared__ float ldtot[16];

  const int tid = threadIdx.x;
  const int w = tid >> 6;
  const int lane = tid & 63;
  const int r0 = blockIdx.x * 16;

  // GEMM1 lane mapping: 32 col-groups x 2 row-groups
  const int cgrp = lane & 31;   // cols cgrp*4 .. +3 (of 128 hidden)
  const int rgrp = lane >> 5;   // rows rgrp*8 .. +7
  // GEMM2 lane mapping: 16 col-groups x 4 row-groups
  const int cg2 = lane & 15;    // cols cg2*4 .. +3 (of 64 out dims)
  const int rg2 = lane >> 4;    // rows rg2*4 .. +3

  for (int e = tid; e < 16 * 64; e += 256) xs[e >> 6][e & 63] = x_in[(size_t)r0 * 64 + e];
  if (tid < 16) ldtot[tid] = 0.f;
  __syncthreads();

  for (int f = 0; f < NFLOWS; ++f) {
    float yacc[4][4];
    #pragma unroll
    for (int a = 0; a < 4; ++a)
      #pragma unroll
      for (int b = 0; b < 4; ++b) yacc[a][b] = 0.f;
    float ldacc[8];
    #pragma unroll
    for (int a = 0; a < 8; ++a) ldacc[a] = 0.f;

    const float gatev = (f < NFLOWS - 1) ? gates[f] : 0.f;
    const float spg = (f < NFLOWS - 1) ? softplus_f(gatev) : 0.f;

    for (int it = 0; it < 16; ++it) {
      const int i = it * 4 + w;           // hidden block (dim index)

      // ---- GEMM1: h[16][128] for this block, fp32 FMA, bf16 weights ----
      float acc1[8][4];
      #pragma unroll
      for (int a = 0; a < 8; ++a)
        #pragma unroll
        for (int b = 0; b < 4; ++b) acc1[a][b] = 0.f;
      const __hip_bfloat16* w1p = wn1b + ((size_t)(f * HID + i * NHID + cgrp * 4)) * DIMF;
      #pragma unroll
      for (int k8 = 0; k8 < 8; ++k8) {
        uint4 rw[4];
        #pragma unroll
        for (int cc = 0; cc < 4; ++cc)
          rw[cc] = *(const uint4*)(w1p + (size_t)cc * DIMF + k8 * 8);
        #pragma unroll
        for (int kp = 0; kp < 4; ++kp) {
          float wl[4], wh[4];
          #pragma unroll
          for (int cc = 0; cc < 4; ++cc) {
            u32 u = ((const u32*)&rw[cc])[kp];
            wl[cc] = bflo(u); wh[cc] = bfhi(u);
          }
          #pragma unroll
          for (int rr = 0; rr < 8; ++rr) {
            float xl = xs[rgrp * 8 + rr][k8 * 8 + 2 * kp];
            float xh = xs[rgrp * 8 + rr][k8 * 8 + 2 * kp + 1];
            #pragma unroll
            for (int cc = 0; cc < 4; ++cc) {
              acc1[rr][cc] = fmaf(xl, wl[cc], acc1[rr][cc]);
              acc1[rr][cc] = fmaf(xh, wh[cc], acc1[rr][cc]);
            }
          }
        }
      }

      // ---- elementwise: tanh, grad, fixed-max lse partial, t -> LDS ----
      const int hk = f * HID + i * NHID + cgrp * 4;
      float b1v[4], cv[4];
      #pragma unroll
      for (int cc = 0; cc < 4; ++cc) { b1v[cc] = b1[hk + cc]; cv[cc] = cvec[hk + cc]; }
      const float Mi = cmax[f * DIMF + i];
      float sacc[8];
      #pragma unroll
      for (int a = 0; a < 8; ++a) sacc[a] = 0.f;
      #pragma unroll
      for (int rr = 0; rr < 8; ++rr) {
        float tv[4];
        #pragma unroll
        for (int cc = 0; cc < 4; ++cc) {
          float h = acc1[rr][cc] + b1v[cc];
          float hc = fminf(fmaxf(h, -40.f), 40.f);
          float u = __expf(2.f * hc);
          float t = 1.f - __fdividef(2.f, u + 1.f);          // tanh(h)
          float invu = __expf(-2.f * hc);
          float g = -2.f * (hc - 0.6931471805599453f + log1pf(invu)); // log(1-tanh^2)
          sacc[rr] += __expf(cv[cc] + g - Mi);
          tv[cc] = t;
        }
        float4 tq; tq.x = tv[0]; tq.y = tv[1]; tq.z = tv[2]; tq.w = tv[3];
        *(float4*)&ts[w][rgrp * 8 + rr][cgrp * 4] = tq;
      }
      asm volatile("s_waitcnt lgkmcnt(0)" ::: "memory"); // wave-private LDS RAW

      // row sums over the 32 col-groups (lanes with same rgrp)
      #pragma unroll
      for (int m = 1; m < 32; m <<= 1) {
        #pragma unroll
        for (int rr = 0; rr < 8; ++rr) sacc[rr] += __shfl_xor(sacc[rr], m, 64);
      }
      #pragma unroll
      for (int rr = 0; rr < 8; ++rr) {
        float grad = Mi + __logf(sacc[rr]);
        float term = (f < NFLOWS - 1) ? (softplus_f(grad + gatev) - spg) : grad;
        ldacc[rr] += term;
      }

      // ---- GEMM2 partial: y[16][64] += t[16][128] * wn2^T ----
      const __hip_bfloat16* w2p = wn2b + ((size_t)(f * DIMF + cg2 * 4)) * HID + i * NHID;
      #pragma unroll
      for (int k8 = 0; k8 < 16; ++k8) {
        uint4 rw[4];
        #pragma unroll
        for (int cc = 0; cc < 4; ++cc)
          rw[cc] = *(const uint4*)(w2p + (size_t)cc * HID + k8 * 8);
        #pragma unroll
        for (int kp = 0; kp < 4; ++kp) {
          float wl[4], wh[4];
          #pragma unroll
          for (int cc = 0; cc < 4; ++cc) {
            u32 u = ((const u32*)&rw[cc])[kp];
            wl[cc] = bflo(u); wh[cc] = bfhi(u);
          }
          #pragma unroll
          for (int rr = 0; rr < 4; ++rr) {
            float tl = ts[w][rg2 * 4 + rr][k8 * 8 + 2 * kp];
            float th = ts[w][rg2 * 4 + rr][k8 * 8 + 2 * kp + 1];
            #pragma unroll
            for (int cc = 0; cc < 4; ++cc) {
              yacc[rr][cc] = fmaf(tl, wl[cc], yacc[rr][cc]);
              yacc[rr][cc] = fmaf(th, wh[cc], yacc[rr][cc]);
            }
          }
        }
      }
    } // hidden loop

    // stage per-wave partials
    #pragma unroll
    for (int rr = 0; rr < 4; ++rr) {
      float4 q; q.x = yacc[rr][0]; q.y = yacc[rr][1]; q.z = yacc[rr][2]; q.w = yacc[rr][3];
      *(float4*)&yp[w][rg2 * 4 + rr][cg2 * 4] = q;
    }
    if ((lane & 31) == 0) {
      #pragma unroll
      for (int rr = 0; rr < 8; ++rr) ldp[w][rgrp * 8 + rr] = ldacc[rr];
    }
    __syncthreads();

    // reduce across waves + epilogue
    float s = 0.f;
    if (f < NFLOWS - 1) s = __fdividef(1.f, 1.f + __expf(-gatev));
    float nv[4]; int ridx[4], jidx[4];
    #pragma unroll
    for (int q = 0; q < 4; ++q) {
      int e = tid + q * 256;
      int r = e >> 6, j = e & 63;
      float yv = b2[f * DIMF + j];
      #pragma unroll
      for (int ww = 0; ww < 4; ++ww) yv += yp[ww][r][j];
      if (f < NFLOWS - 1) {
        nv[q] = s * yv + (1.f - s) * xs[r][j];   // gated output
        ridx[q] = r; jidx[q] = 63 - j;           // flip for next flow
      } else {
        out[(size_t)(r0 + r) * 64 + j] = yv;     // last flow: raw y, no flip
      }
    }
    if (tid < 16) {
      float acc = ldtot[tid];
      #pragma unroll
      for (int ww = 0; ww < 4; ++ww) acc += ldp[ww][tid];
      ldtot[tid] = acc;
    }
    __syncthreads();
    if (f < NFLOWS - 1) {
      #pragma unroll
      for (int q = 0; q < 4; ++q) xs[ridx[q]][jidx[q]] = nv[q];
    }
    __syncthreads();
  } // flows

  if (tid < 16) out[(size_t)BATCHN * DIMF + r0 + tid] = ldtot[tid];
}

extern "C" void kernel_launch(void* const* d_in, const int* in_sizes, int n_in,
                              void* d_out, int out_size, void* d_ws, size_t ws_size,
                              hipStream_t stream)
{
  const float* x     = (const float*)d_in[0];
  const float* W1    = (const float*)d_in[1];
  const float* d1    = (const float*)d_in[2];
  const float* b1    = (const float*)d_in[3];
  const float* W2    = (const float*)d_in[4];
  const float* d2    = (const float*)d_in[5];
  const float* b2    = (const float*)d_in[6];
  const float* gates = (const float*)d_in[7];
  float* out = (float*)d_out;

  char* ws = (char*)d_ws;
  __hip_bfloat16* wn1b = (__hip_bfloat16*)ws;                 // 5*8192*64*2  = 5,242,880
  __hip_bfloat16* wn2b = (__hip_bfloat16*)(ws + 5242880);     // 5*64*8192*2  = 5,242,880
  float* cvec  = (float*)(ws + 10485760);                     // 5*8192*4     =   163,840
  float* cmaxp = (float*)(ws + 10649600);                     // 5*64*4       =     1,280
  float* g1    = (float*)(ws + 10650880);                     // 5*8192*4     =   163,840

  hipLaunchKernelGGL(prep1_kernel, dim3(10240), dim3(256), 0, stream, W1, d1, wn1b, g1);
  hipLaunchKernelGGL(prep2_kernel, dim3(320), dim3(256), 0, stream, W2, d2, g1, wn2b, cvec, cmaxp);
  hipLaunchKernelGGL(bnaf_main_kernel, dim3(256), dim3(256), 0, stream,
                     x, b1, b2, gates, wn1b, wn2b, cvec, cmaxp, out);
}

// Round 2
// 415.279 us; speedup vs baseline: 4.5078x; 4.5078x over previous
//
#include <hip/hip_runtime.h>
#include <hip/hip_bf16.h>
#include <math.h>

#define NFLOWS 5
#define DIMF 64
#define HID 8192
#define BATCHN 4096

typedef unsigned int u32;
typedef __bf16 bf16x8 __attribute__((ext_vector_type(8)));
typedef float f32x4 __attribute__((ext_vector_type(4)));

__device__ __forceinline__ short f2bf_s(float x){
  u32 b = __float_as_uint(x);
  b += 0x7fff + ((b >> 16) & 1);          // RNE
  return (short)(b >> 16);
}
__device__ __forceinline__ float softplus_f(float z){
  return fmaxf(z, 0.f) + log1pf(__expf(-fabsf(z)));
}

// ---------------- prep1: wn1 (bf16) + g1 ----------------
__global__ __launch_bounds__(256) void prep1_kernel(
    const float* __restrict__ W1, const float* __restrict__ d1,
    __hip_bfloat16* __restrict__ wn1b, float* __restrict__ g1)
{
  int w = threadIdx.x >> 6;
  int lane = threadIdx.x & 63;
  int R = blockIdx.x * 4 + w;            // 0 .. 5*8192-1
  int rl = R & (HID - 1);
  int blk = rl >> 7;                     // dim index of this hidden row
  float Wv = W1[(size_t)R * DIMF + lane];
  float wv;
  if (lane == blk)      wv = __expf(Wv);
  else if (lane < blk)  wv = Wv;
  else                  wv = 0.f;
  float sq = wv * wv;
  #pragma unroll
  for (int m = 1; m < 64; m <<= 1) sq += __shfl_xor(sq, m, 64);
  float d1v = d1[R];
  float sc = __expf(d1v) * rsqrtf(sq);
  wn1b[(size_t)R * DIMF + lane] = __float2bfloat16(wv * sc);
  if (lane == blk) g1[R] = d1v + Wv - 0.5f * __logf(sq);
}

// ---------------- prep2: wn2 (bf16) + expc4 + cmax ----------------
// block per (flow f, out-row i); expc4[k] = 4*exp(c[k]-cmax_i) on diagonal k
__global__ __launch_bounds__(256) void prep2_kernel(
    const float* __restrict__ W2, const float* __restrict__ d2,
    const float* __restrict__ g1,
    __hip_bfloat16* __restrict__ wn2b, float* __restrict__ expc4,
    float* __restrict__ cmax)
{
  __shared__ float red[256];
  int f = blockIdx.x >> 6;
  int i = blockIdx.x & 63;
  int tid = threadIdx.x;
  const float* Wrow = W2 + ((size_t)(f * DIMF + i)) * HID;
  float d2v = d2[f * DIMF + i];
  float part = 0.f;
  for (int k = tid; k < HID; k += 256) {
    float Wv = Wrow[k];
    int kb = k >> 7;
    float wv = (kb == i) ? __expf(Wv) : ((kb < i) ? Wv : 0.f);
    part += wv * wv;
  }
  red[tid] = part; __syncthreads();
  for (int s = 128; s > 0; s >>= 1) {
    if (tid < s) red[tid] += red[tid + s];
    __syncthreads();
  }
  float wsn = red[0];
  __syncthreads();
  float ls = __logf(wsn);
  float sc = __expf(d2v) * rsqrtf(wsn);
  float lmax = -1e30f;
  int kheld = -1; float cvheld = 0.f;
  for (int k = tid; k < HID; k += 256) {
    float Wv = Wrow[k];
    int kb = k >> 7;
    float wv = (kb == i) ? __expf(Wv) : ((kb < i) ? Wv : 0.f);
    wn2b[((size_t)(f * DIMF + i)) * HID + k] = __float2bfloat16(wv * sc);
    if (kb == i) {
      float cv = g1[f * HID + k] + d2v + Wv - 0.5f * ls;   // g1+g2 combined
      cvheld = cv; kheld = k;
      lmax = fmaxf(lmax, cv);
    }
  }
  red[tid] = lmax; __syncthreads();
  for (int s = 128; s > 0; s >>= 1) {
    if (tid < s) red[tid] = fmaxf(red[tid], red[tid + s]);
    __syncthreads();
  }
  float M = red[0];
  if (kheld >= 0) expc4[f * HID + kheld] = 4.f * __expf(cvheld - M);
  if (tid == 0) cmax[f * DIMF + i] = M;
}

// ---------------- main fused kernel: all 5 flows, MFMA ----------------
// 256 blocks x 512 threads (8 waves). Block owns 16 batch rows; each wave
// owns 8 of the 64 hidden blocks. x persists in LDS across flows.
__global__ __launch_bounds__(512, 2) void bnaf_main_kernel(
    const float* __restrict__ x_in,
    const float* __restrict__ b1, const float* __restrict__ b2,
    const float* __restrict__ gates,
    const __hip_bfloat16* __restrict__ wn1b,
    const __hip_bfloat16* __restrict__ wn2b,
    const float* __restrict__ expc4, const float* __restrict__ cmax,
    float* __restrict__ out)
{
  // LDS map (bytes):
  //   0     .. 4351   xs   fp32 x [16][68] (stride-68 pad)
  //   4352  .. 6527   xb   bf16 A-frags of x, kq-padded stride 136 elems
  //   6528  .. 41343  ts   per-wave bf16 A-frags of t (2176 shorts each);
  //                        reused as per-wave y-partials (1024 f32) at flow end
  //   41344 .. 41855  ldp  [8][16] f32
  __shared__ __attribute__((aligned(16))) char smem[41856];
  float* xs  = (float*)smem;
  short* xbS = (short*)(smem + 4352);
  short* tsA = (short*)(smem + 6528);
  float* ldp = (float*)(smem + 41344);

  const int tid  = threadIdx.x;
  const int w    = tid >> 6;
  const int lane = tid & 63;
  const int c16  = lane & 15;     // MFMA n / m fragment index
  const int q    = lane >> 4;     // MFMA k-quad
  const int r0   = blockIdx.x * 16;

  short* tsw = tsA + w * 2176;

  for (int e = tid; e < 1024; e += 512) {
    int row = e >> 6, col = e & 63;
    float v = x_in[((size_t)(r0 + row) << 6) | col];
    xs[row * 68 + col] = v;
    xbS[(col >> 3) * 136 + row * 8 + (col & 7)] = f2bf_s(v);
  }
  float ldtot = 0.f;
  __syncthreads();

  #pragma unroll 1
  for (int f = 0; f < NFLOWS; ++f) {
    const float gatev = (f < NFLOWS - 1) ? gates[f] : 0.f;
    const float spg   = (f < NFLOWS - 1) ? softplus_f(gatev) : 0.f;

    // x A-frags for both k-steps (K=64), shared by all iters of this flow
    const bf16x8 xa0 = *(const bf16x8*)(xbS + q * 136 + c16 * 8);
    const bf16x8 xa1 = *(const bf16x8*)(xbS + (4 + q) * 136 + c16 * 8);

    f32x4 yacc[4];
    #pragma unroll
    for (int n = 0; n < 4; ++n) yacc[n] = f32x4{0.f, 0.f, 0.f, 0.f};
    float ldacc[4] = {0.f, 0.f, 0.f, 0.f};

    #pragma unroll 1
    for (int ii = 0; ii < 8; ++ii) {
      const int i = ii * 8 + w;                 // hidden block (dim index)

      // ---- GEMM1: h tile 16x128 via MFMA, weights streamed from L2 ----
      const __hip_bfloat16* w1base =
          wn1b + (((size_t)(f * HID + i * 128 + c16)) << 6) + q * 8;
      f32x4 d[8];
      #pragma unroll
      for (int nt = 0; nt < 8; ++nt) {
        bf16x8 bw0 = *(const bf16x8*)(w1base + ((size_t)nt << 10));
        bf16x8 bw1 = *(const bf16x8*)(w1base + ((size_t)nt << 10) + 32);
        f32x4 z = {0.f, 0.f, 0.f, 0.f};
        z = __builtin_amdgcn_mfma_f32_16x16x32_bf16(xa0, bw0, z, 0, 0, 0);
        d[nt] = __builtin_amdgcn_mfma_f32_16x16x32_bf16(xa1, bw1, z, 0, 0, 0);
      }

      // ---- elementwise: tanh + lse contributions, t -> LDS A-frag ----
      const int hb = f * HID + i * 128 + c16;
      float sacc[4] = {0.f, 0.f, 0.f, 0.f};
      #pragma unroll
      for (int nt = 0; nt < 8; ++nt) {
        float b1v = b1[hb + nt * 16];
        float ec4 = expc4[hb + nt * 16];
        #pragma unroll
        for (int r = 0; r < 4; ++r) {
          float h = d[nt][r] + b1v;
          h = fminf(fmaxf(h, -30.f), 30.f);
          float u = __expf(2.f * h);
          float v = __builtin_amdgcn_rcpf(u + 1.f);
          float t = fmaf(-2.f, v, 1.f);                  // tanh(h)
          sacc[r] = fmaf(ec4 * u, v * v, sacc[r]);       // e^{c-M}·(1-t²)
          tsw[(nt * 2 + (c16 >> 3)) * 136 + (q * 4 + r) * 8 + (c16 & 7)] = f2bf_s(t);
        }
      }
      asm volatile("s_waitcnt lgkmcnt(0)" ::: "memory"); // wave-private LDS RAW

      // row-sum over the 16 fragment columns (lanes sharing q)
      #pragma unroll
      for (int m = 1; m < 16; m <<= 1) {
        #pragma unroll
        for (int r = 0; r < 4; ++r) sacc[r] += __shfl_xor(sacc[r], m, 64);
      }
      const float Mi = cmax[f * DIMF + i];
      #pragma unroll
      for (int r = 0; r < 4; ++r) {
        float grad = Mi + __logf(sacc[r]);
        ldacc[r] += (f < NFLOWS - 1) ? (softplus_f(grad + gatev) - spg) : grad;
      }

      // ---- GEMM2 partial: y[16][64] += t[16][128] · wn2^T ----
      const __hip_bfloat16* w2base =
          wn2b + (((size_t)(f * DIMF + c16)) << 13) + i * 128 + q * 8;
      #pragma unroll
      for (int ks = 0; ks < 4; ++ks) {
        bf16x8 ta = *(const bf16x8*)(tsw + (ks * 4 + q) * 136 + c16 * 8);
        #pragma unroll
        for (int nt2 = 0; nt2 < 4; ++nt2) {
          bf16x8 wb = *(const bf16x8*)(w2base + ((size_t)nt2 << 17) + ks * 32);
          yacc[nt2] = __builtin_amdgcn_mfma_f32_16x16x32_bf16(ta, wb, yacc[nt2], 0, 0, 0);
        }
      }
    } // hidden blocks

    // ---- stage per-wave partials (y into ts region, C-frag linear) ----
    asm volatile("s_waitcnt lgkmcnt(0)" ::: "memory");
    float* ypw = (float*)(smem + 6528 + w * 4352);
    #pragma unroll
    for (int nt2 = 0; nt2 < 4; ++nt2)
      #pragma unroll
      for (int r = 0; r < 4; ++r)
        ypw[(nt2 * 4 + r) * 64 + lane] = yacc[nt2][r];
    if (c16 == 0) {
      #pragma unroll
      for (int r = 0; r < 4; ++r) ldp[w * 16 + q * 4 + r] = ldacc[r];
    }
    __syncthreads();

    // ---- epilogue: reduce 8 waves, bias, gate, flip ----
    float sgate = 0.f;
    if (f < NFLOWS - 1) sgate = __builtin_amdgcn_rcpf(1.f + __expf(-gatev));
    float nx[2]; int nrow[2], ncol[2];
    #pragma unroll
    for (int p = 0; p < 2; ++p) {
      int e = tid + p * 512;
      int row = e >> 6, col = e & 63;
      int li  = (col & 15) | ((row & 12) << 2);
      int idx = ((col >> 4) * 4 + (row & 3)) * 64 + li;
      float v = b2[f * DIMF + col];
      #pragma unroll
      for (int ww = 0; ww < 8; ++ww)
        v += ((const float*)(smem + 6528 + ww * 4352))[idx];
      if (f < NFLOWS - 1) {
        float xv = xs[row * 68 + col];
        nx[p] = fmaf(sgate, v - xv, xv);        // s*y + (1-s)*x
        nrow[p] = row; ncol[p] = 63 - col;      // flip for next flow
      } else {
        out[((size_t)(r0 + row) << 6) | col] = v;
      }
    }
    if (tid < 16) {
      float a = 0.f;
      #pragma unroll
      for (int ww = 0; ww < 8; ++ww) a += ldp[ww * 16 + tid];
      ldtot += a;
    }
    __syncthreads();
    if (f < NFLOWS - 1) {
      #pragma unroll
      for (int p = 0; p < 2; ++p) {
        xs[nrow[p] * 68 + ncol[p]] = nx[p];
        xbS[(ncol[p] >> 3) * 136 + nrow[p] * 8 + (ncol[p] & 7)] = f2bf_s(nx[p]);
      }
      __syncthreads();
    }
  } // flows

  if (tid < 16) out[(size_t)BATCHN * DIMF + r0 + tid] = ldtot;
}

extern "C" void kernel_launch(void* const* d_in, const int* in_sizes, int n_in,
                              void* d_out, int out_size, void* d_ws, size_t ws_size,
                              hipStream_t stream)
{
  const float* x     = (const float*)d_in[0];
  const float* W1    = (const float*)d_in[1];
  const float* d1    = (const float*)d_in[2];
  const float* b1    = (const float*)d_in[3];
  const float* W2    = (const float*)d_in[4];
  const float* d2    = (const float*)d_in[5];
  const float* b2    = (const float*)d_in[6];
  const float* gates = (const float*)d_in[7];
  float* out = (float*)d_out;

  char* ws = (char*)d_ws;
  __hip_bfloat16* wn1b = (__hip_bfloat16*)ws;                 // 5,242,880 B
  __hip_bfloat16* wn2b = (__hip_bfloat16*)(ws + 5242880);     // 5,242,880 B
  float* expc4 = (float*)(ws + 10485760);                     //   163,840 B
  float* cmaxp = (float*)(ws + 10649600);                     //     1,280 B
  float* g1    = (float*)(ws + 10650880);                     //   163,840 B

  hipLaunchKernelGGL(prep1_kernel, dim3(10240), dim3(256), 0, stream, W1, d1, wn1b, g1);
  hipLaunchKernelGGL(prep2_kernel, dim3(320), dim3(256), 0, stream, W2, d2, g1, wn2b, expc4, cmaxp);
  hipLaunchKernelGGL(bnaf_main_kernel, dim3(256), dim3(512), 0, stream,
                     x, b1, b2, gates, wn1b, wn2b, expc4, cmaxp, out);
}

// Round 3
// 285.638 us; speedup vs baseline: 6.5538x; 1.4539x over previous
//
#include <hip/hip_runtime.h>
#include <hip/hip_bf16.h>
#include <math.h>

#define NFLOWS 5
#define DIMF 64
#define HID 8192
#define BATCHN 4096

typedef unsigned int u32;
typedef __bf16 bf16x8 __attribute__((ext_vector_type(8)));
typedef float f32x4 __attribute__((ext_vector_type(4)));

__device__ __forceinline__ short f2bf_s(float x){
  u32 b = __float_as_uint(x);
  b += 0x7fff + ((b >> 16) & 1);          // RNE
  return (short)(b >> 16);
}
__device__ __forceinline__ float softplus_f(float z){
  return fmaxf(z, 0.f) + log1pf(__expf(-fabsf(z)));
}

// ---------------- prep1: wn1 -> lane-swizzled bf16 frags + g1 ----------------
// one 64-lane wave per row R of W1; lane = input col k (0..63).
// dest layout: [f][i(64)][nt(8)][ks2(2)][lane(64)][8]  (elements)
__global__ __launch_bounds__(256) void prep1_kernel(
    const float* __restrict__ W1, const float* __restrict__ d1,
    short* __restrict__ wn1s, float* __restrict__ g1)
{
  int w = threadIdx.x >> 6;
  int k = threadIdx.x & 63;
  int R = blockIdx.x * 4 + w;            // 0 .. 5*8192-1
  int rl = R & (HID - 1);
  int blk = rl >> 7;                     // dim index of this hidden row
  float Wv = W1[(size_t)R * DIMF + k];
  float wv;
  if (k == blk)      wv = __expf(Wv);
  else if (k < blk)  wv = Wv;
  else               wv = 0.f;
  float sq = wv * wv;
  #pragma unroll
  for (int m = 1; m < 64; m <<= 1) sq += __shfl_xor(sq, m, 64);
  float d1v = d1[R];
  float sc = __expf(d1v) * rsqrtf(sq);
  int f   = R >> 13;
  int i   = rl >> 7;
  int rem = rl & 127;
  int nt  = rem >> 4;
  int n16 = rem & 15;
  int ks2 = k >> 5;
  int q   = (k & 31) >> 3;
  int j   = k & 7;
  size_t dst = ((((size_t)(f * 64 + i) * 8 + nt) * 2 + ks2) << 9)
             + ((q * 16 + n16) << 3) + j;
  wn1s[dst] = f2bf_s(wv * sc);
  if (k == blk) g1[R] = d1v + Wv - 0.5f * __logf(sq);
}

// ---------------- prep2: wn2 -> lane-swizzled bf16 frags + expc4 + cmax ------
// block per (flow f, out-row iRow).
// dest layout: [f][i(64)][ks(4)][nt2(4)][lane(64)][8]  (elements)
__global__ __launch_bounds__(256) void prep2_kernel(
    const float* __restrict__ W2, const float* __restrict__ d2,
    const float* __restrict__ g1,
    short* __restrict__ wn2s, float* __restrict__ expc4,
    float* __restrict__ cmax)
{
  __shared__ float red[256];
  int f = blockIdx.x >> 6;
  int iRow = blockIdx.x & 63;
  int tid = threadIdx.x;
  const float* Wrow = W2 + ((size_t)(f * DIMF + iRow)) * HID;
  float d2v = d2[f * DIMF + iRow];
  float part = 0.f;
  for (int k = tid; k < HID; k += 256) {
    float Wv = Wrow[k];
    int kb = k >> 7;
    float wv = (kb == iRow) ? __expf(Wv) : ((kb < iRow) ? Wv : 0.f);
    part += wv * wv;
  }
  red[tid] = part; __syncthreads();
  for (int s = 128; s > 0; s >>= 1) {
    if (tid < s) red[tid] += red[tid + s];
    __syncthreads();
  }
  float wsn = red[0];
  __syncthreads();
  float ls = __logf(wsn);
  float sc = __expf(d2v) * rsqrtf(wsn);
  float lmax = -1e30f;
  int kheld = -1; float cvheld = 0.f;
  int nt2 = iRow >> 4, c16r = iRow & 15;
  for (int k = tid; k < HID; k += 256) {
    float Wv = Wrow[k];
    int kb = k >> 7;
    float wv = (kb == iRow) ? __expf(Wv) : ((kb < iRow) ? Wv : 0.f);
    int i = k >> 7, ks = (k >> 5) & 3, q = (k >> 3) & 3, j = k & 7;
    size_t dst = ((((size_t)(f * 64 + i) * 4 + ks) * 4 + nt2) << 9)
               + ((q * 16 + c16r) << 3) + j;
    wn2s[dst] = f2bf_s(wv * sc);
    if (kb == iRow) {
      float cv = g1[f * HID + k] + d2v + Wv - 0.5f * ls;   // g1+g2 combined
      cvheld = cv; kheld = k;
      lmax = fmaxf(lmax, cv);
    }
  }
  red[tid] = lmax; __syncthreads();
  for (int s = 128; s > 0; s >>= 1) {
    if (tid < s) red[tid] = fmaxf(red[tid], red[tid + s]);
    __syncthreads();
  }
  float M = red[0];
  if (kheld >= 0) expc4[f * HID + kheld] = 4.f * __expf(cvheld - M);
  if (tid == 0) cmax[f * DIMF + iRow] = M;
}

// ---------------- main fused kernel: all 5 flows, MFMA ----------------
// 256 blocks x 1024 threads (16 waves). Block owns 16 batch rows; each wave
// owns 4 of the 64 hidden blocks. x persists in LDS across flows.
__global__ __launch_bounds__(1024, 4) void bnaf_main_kernel(
    const float* __restrict__ x_in,
    const float* __restrict__ b1, const float* __restrict__ b2,
    const float* __restrict__ gates,
    const short* __restrict__ wn1s,
    const short* __restrict__ wn2s,
    const float* __restrict__ expc4, const float* __restrict__ cmax,
    float* __restrict__ out)
{
  // LDS map (bytes):
  //   0     .. 4351    xs   fp32 x [16][68]
  //   4352  .. 6527    xb   bf16 A-frags of x (kb-stride 136 elems)
  //   6528  .. 76159   ts   per-wave bf16 A-frags of t (2176 shorts = 4352 B
  //                         each, 16 waves); reused as y-partials (1024 f32)
  //   76160 .. 77183   ldp  [16][16] f32
  __shared__ __attribute__((aligned(16))) char smem[77184];
  float* xs  = (float*)smem;
  short* xbS = (short*)(smem + 4352);
  float* ldp = (float*)(smem + 76160);

  const int tid  = threadIdx.x;
  const int w    = tid >> 6;      // wave 0..15
  const int lane = tid & 63;
  const int c16  = lane & 15;
  const int q    = lane >> 4;
  const int r0   = blockIdx.x * 16;

  short* tsw = (short*)(smem + 6528 + w * 4352);

  for (int e = tid; e < 1024; e += 1024) {
    int row = e >> 6, col = e & 63;
    float v = x_in[((size_t)(r0 + row) << 6) | col];
    xs[row * 68 + col] = v;
    xbS[(col >> 3) * 136 + row * 8 + (col & 7)] = f2bf_s(v);
  }
  float ldtot = 0.f;
  __syncthreads();

  #pragma unroll 1
  for (int f = 0; f < NFLOWS; ++f) {
    const float gatev = (f < NFLOWS - 1) ? gates[f] : 0.f;
    const float spg   = (f < NFLOWS - 1) ? softplus_f(gatev) : 0.f;

    // x A-frags for both k-steps (K=64), shared by all iters of this flow
    const bf16x8 xa0 = *(const bf16x8*)(xbS + q * 136 + c16 * 8);
    const bf16x8 xa1 = *(const bf16x8*)(xbS + (4 + q) * 136 + c16 * 8);

    f32x4 yacc[4];
    #pragma unroll
    for (int n = 0; n < 4; ++n) yacc[n] = f32x4{0.f, 0.f, 0.f, 0.f};
    float ldacc[4] = {0.f, 0.f, 0.f, 0.f};

    #pragma unroll 1
    for (int ii = 0; ii < 4; ++ii) {
      const int i = ii * 16 + w;                 // hidden block (dim index)

      // ---- GEMM1: h tile 16x128 via MFMA; 1KB coalesced frag loads ----
      const short* p1l = wn1s + (((size_t)(f * 64 + i)) << 13) + lane * 8;
      f32x4 d[8];
      #pragma unroll
      for (int nt = 0; nt < 8; ++nt) {
        bf16x8 bw0 = *(const bf16x8*)(p1l + nt * 1024);
        bf16x8 bw1 = *(const bf16x8*)(p1l + nt * 1024 + 512);
        f32x4 z = {0.f, 0.f, 0.f, 0.f};
        z = __builtin_amdgcn_mfma_f32_16x16x32_bf16(xa0, bw0, z, 0, 0, 0);
        d[nt] = __builtin_amdgcn_mfma_f32_16x16x32_bf16(xa1, bw1, z, 0, 0, 0);
      }

      // ---- elementwise: tanh + lse contributions, t -> LDS A-frag ----
      const int hb = f * HID + i * 128 + c16;
      float sacc[4] = {0.f, 0.f, 0.f, 0.f};
      #pragma unroll
      for (int nt = 0; nt < 8; ++nt) {
        float b1v = b1[hb + nt * 16];
        float ec4 = expc4[hb + nt * 16];
        #pragma unroll
        for (int r = 0; r < 4; ++r) {
          float h = d[nt][r] + b1v;
          h = fminf(fmaxf(h, -30.f), 30.f);
          float u = __expf(2.f * h);
          float v = __builtin_amdgcn_rcpf(u + 1.f);
          float t = fmaf(-2.f, v, 1.f);                  // tanh(h)
          sacc[r] = fmaf(ec4 * u, v * v, sacc[r]);       // e^{c-M}·(1-t²)
          tsw[(nt * 2 + (c16 >> 3)) * 136 + (q * 4 + r) * 8 + (c16 & 7)] = f2bf_s(t);
        }
      }
      asm volatile("s_waitcnt lgkmcnt(0)" ::: "memory"); // wave-private LDS RAW

      // row-sum over the 16 fragment columns (lanes sharing q)
      #pragma unroll
      for (int m = 1; m < 16; m <<= 1) {
        #pragma unroll
        for (int r = 0; r < 4; ++r) sacc[r] += __shfl_xor(sacc[r], m, 64);
      }
      const float Mi = cmax[f * DIMF + i];
      #pragma unroll
      for (int r = 0; r < 4; ++r) {
        float grad = Mi + __logf(sacc[r]);
        ldacc[r] += (f < NFLOWS - 1) ? (softplus_f(grad + gatev) - spg) : grad;
      }

      // ---- GEMM2 partial: y[16][64] += t[16][128]·wn2^T; 1KB frag loads ----
      const short* p2l = wn2s + (((size_t)(f * 64 + i)) << 13) + lane * 8;
      #pragma unroll
      for (int ks = 0; ks < 4; ++ks) {
        bf16x8 ta = *(const bf16x8*)(tsw + (ks * 4 + q) * 136 + c16 * 8);
        #pragma unroll
        for (int nt2 = 0; nt2 < 4; ++nt2) {
          bf16x8 wb = *(const bf16x8*)(p2l + (ks * 4 + nt2) * 512);
          yacc[nt2] = __builtin_amdgcn_mfma_f32_16x16x32_bf16(ta, wb, yacc[nt2], 0, 0, 0);
        }
      }
    } // hidden blocks

    // ---- stage per-wave partials (y into ts region, C-frag linear) ----
    asm volatile("s_waitcnt lgkmcnt(0)" ::: "memory");
    float* ypw = (float*)(smem + 6528 + w * 4352);
    #pragma unroll
    for (int nt2 = 0; nt2 < 4; ++nt2)
      #pragma unroll
      for (int r = 0; r < 4; ++r)
        ypw[(nt2 * 4 + r) * 64 + lane] = yacc[nt2][r];
    if (c16 == 0) {
      #pragma unroll
      for (int r = 0; r < 4; ++r) ldp[w * 16 + q * 4 + r] = ldacc[r];
    }
    __syncthreads();

    // ---- epilogue: reduce 16 waves, bias, gate, flip ----
    float sgate = 0.f;
    if (f < NFLOWS - 1) sgate = __builtin_amdgcn_rcpf(1.f + __expf(-gatev));
    int row = tid >> 6, col = tid & 63;
    int li  = (col & 15) | ((row & 12) << 2);
    int idx = ((col >> 4) * 4 + (row & 3)) * 64 + li;
    float v = b2[f * DIMF + col];
    #pragma unroll
    for (int ww = 0; ww < 16; ++ww)
      v += ((const float*)(smem + 6528 + ww * 4352))[idx];
    float nx = 0.f; int nrow = 0, ncol = 0;
    if (f < NFLOWS - 1) {
      float xv = xs[row * 68 + col];
      nx = fmaf(sgate, v - xv, xv);        // s*y + (1-s)*x
      nrow = row; ncol = 63 - col;         // flip for next flow
    } else {
      out[((size_t)(r0 + row) << 6) | col] = v;
    }
    if (tid < 16) {
      float a = 0.f;
      #pragma unroll
      for (int ww = 0; ww < 16; ++ww) a += ldp[ww * 16 + tid];
      ldtot += a;
    }
    __syncthreads();
    if (f < NFLOWS - 1) {
      xs[nrow * 68 + ncol] = nx;
      xbS[(ncol >> 3) * 136 + nrow * 8 + (ncol & 7)] = f2bf_s(nx);
      __syncthreads();
    }
  } // flows

  if (tid < 16) out[(size_t)BATCHN * DIMF + r0 + tid] = ldtot;
}

extern "C" void kernel_launch(void* const* d_in, const int* in_sizes, int n_in,
                              void* d_out, int out_size, void* d_ws, size_t ws_size,
                              hipStream_t stream)
{
  const float* x     = (const float*)d_in[0];
  const float* W1    = (const float*)d_in[1];
  const float* d1    = (const float*)d_in[2];
  const float* b1    = (const float*)d_in[3];
  const float* W2    = (const float*)d_in[4];
  const float* d2    = (const float*)d_in[5];
  const float* b2    = (const float*)d_in[6];
  const float* gates = (const float*)d_in[7];
  float* out = (float*)d_out;

  char* ws = (char*)d_ws;
  short* wn1s  = (short*)ws;                                  // 5,242,880 B
  short* wn2s  = (short*)(ws + 5242880);                      // 5,242,880 B
  float* expc4 = (float*)(ws + 10485760);                     //   163,840 B
  float* cmaxp = (float*)(ws + 10649600);                     //     1,280 B
  float* g1    = (float*)(ws + 10650880);                     //   163,840 B

  hipLaunchKernelGGL(prep1_kernel, dim3(10240), dim3(256), 0, stream, W1, d1, wn1s, g1);
  hipLaunchKernelGGL(prep2_kernel, dim3(320), dim3(256), 0, stream, W2, d2, g1, wn2s, expc4, cmaxp);
  hipLaunchKernelGGL(bnaf_main_kernel, dim3(256), dim3(1024), 0, stream,
                     x, b1, b2, gates, wn1s, wn2s, expc4, cmaxp, out);
}

// Round 4
// 284.536 us; speedup vs baseline: 6.5791x; 1.0039x over previous
//
#include <hip/hip_runtime.h>
#include <hip/hip_bf16.h>
#include <math.h>

#define NFLOWS 5
#define DIMF 64
#define HID 8192
#define BATCHN 4096

typedef unsigned int u32;
typedef __bf16 bf16x8 __attribute__((ext_vector_type(8)));
typedef float f32x4 __attribute__((ext_vector_type(4)));

__device__ __forceinline__ short f2bf_s(float x){
  u32 b = __float_as_uint(x);
  b += 0x7fff + ((b >> 16) & 1);          // RNE
  return (short)(b >> 16);
}
// pack two f32 -> bf16x2 (lo = a, hi = b), RNE
__device__ __forceinline__ u32 pk_bf16(float a, float b){
#if __has_builtin(__builtin_amdgcn_cvt_pk_bf16_f32)
  typedef __bf16 bf16x2_t __attribute__((ext_vector_type(2)));
  bf16x2_t r = __builtin_amdgcn_cvt_pk_bf16_f32(a, b);
  return __builtin_bit_cast(u32, r);
#else
  u32 x = __float_as_uint(a); x += 0x7fff + ((x >> 16) & 1);
  u32 y = __float_as_uint(b); y += 0x7fff + ((y >> 16) & 1);
  return (x >> 16) | (y & 0xffff0000u);
#endif
}
__device__ __forceinline__ float softplus_f(float z){
  return fmaxf(z, 0.f) + log1pf(__expf(-fabsf(z)));
}

// ---------------- prep1: wn1 -> lane-swizzled bf16 frags + g1 ----------------
// dest layout: [f][i(64)][nt(8)][ks2(2)][lane(64)][8]  (elements)
// frag content: lane(c16,q) holds wn1[hidden = i*128+nt*16+c16][feat ks2*32+q*8+j]
__global__ __launch_bounds__(256) void prep1_kernel(
    const float* __restrict__ W1, const float* __restrict__ d1,
    short* __restrict__ wn1s, float* __restrict__ g1)
{
  int w = threadIdx.x >> 6;
  int k = threadIdx.x & 63;
  int R = blockIdx.x * 4 + w;            // 0 .. 5*8192-1
  int rl = R & (HID - 1);
  int blk = rl >> 7;                     // dim index of this hidden row
  float Wv = W1[(size_t)R * DIMF + k];
  float wv;
  if (k == blk)      wv = __expf(Wv);
  else if (k < blk)  wv = Wv;
  else               wv = 0.f;
  float sq = wv * wv;
  #pragma unroll
  for (int m = 1; m < 64; m <<= 1) sq += __shfl_xor(sq, m, 64);
  float d1v = d1[R];
  float sc = __expf(d1v) * rsqrtf(sq);
  int f   = R >> 13;
  int i   = rl >> 7;
  int rem = rl & 127;
  int nt  = rem >> 4;
  int n16 = rem & 15;
  int ks2 = k >> 5;
  int q   = (k & 31) >> 3;
  int j   = k & 7;
  size_t dst = ((((size_t)(f * 64 + i) * 8 + nt) * 2 + ks2) << 9)
             + ((q * 16 + n16) << 3) + j;
  wn1s[dst] = f2bf_s(wv * sc);
  if (k == blk) g1[R] = d1v + Wv - 0.5f * __logf(sq);
}

// ---------------- prep2: wn2 -> lane-swizzled bf16 frags + expc4 + cmax ------
// dest layout: [f][i(64)][ks(4)][mt(4)][lane(64)][8]  (elements)
// frag content: lane(c16,q) holds wn2[out = mt*16+c16][k = i*128+ks*32+q*8+j]
__global__ __launch_bounds__(1024) void prep2_kernel(
    const float* __restrict__ W2, const float* __restrict__ d2,
    const float* __restrict__ g1,
    short* __restrict__ wn2s, float* __restrict__ expc4,
    float* __restrict__ cmax)
{
  __shared__ float red[1024];
  int f = blockIdx.x >> 6;
  int iRow = blockIdx.x & 63;
  int tid = threadIdx.x;
  const float* Wrow = W2 + ((size_t)(f * DIMF + iRow)) * HID;
  float d2v = d2[f * DIMF + iRow];
  float part = 0.f;
  #pragma unroll
  for (int kk = 0; kk < 8; ++kk) {
    int k = tid + kk * 1024;
    float Wv = Wrow[k];
    int kb = k >> 7;
    float wv = (kb == iRow) ? __expf(Wv) : ((kb < iRow) ? Wv : 0.f);
    part += wv * wv;
  }
  red[tid] = part; __syncthreads();
  for (int s = 512; s > 0; s >>= 1) {
    if (tid < s) red[tid] += red[tid + s];
    __syncthreads();
  }
  float wsn = red[0];
  __syncthreads();
  float ls = __logf(wsn);
  float sc = __expf(d2v) * rsqrtf(wsn);
  float lmax = -1e30f;
  int kheld = -1; float cvheld = 0.f;
  int mt2 = iRow >> 4, c16r = iRow & 15;
  #pragma unroll
  for (int kk = 0; kk < 8; ++kk) {
    int k = tid + kk * 1024;
    float Wv = Wrow[k];
    int kb = k >> 7;
    float wv = (kb == iRow) ? __expf(Wv) : ((kb < iRow) ? Wv : 0.f);
    int i = k >> 7, ks = (k >> 5) & 3, q = (k >> 3) & 3, j = k & 7;
    size_t dst = ((((size_t)(f * 64 + i) * 4 + ks) * 4 + mt2) << 9)
               + ((q * 16 + c16r) << 3) + j;
    wn2s[dst] = f2bf_s(wv * sc);
    if (kb == iRow) {
      float cv = g1[f * HID + k] + d2v + Wv - 0.5f * ls;   // g1+g2 combined
      cvheld = cv; kheld = k;
      lmax = fmaxf(lmax, cv);
    }
  }
  red[tid] = lmax; __syncthreads();
  for (int s = 512; s > 0; s >>= 1) {
    if (tid < s) red[tid] = fmaxf(red[tid], red[tid + s]);
    __syncthreads();
  }
  float M = red[0];
  if (kheld >= 0) expc4[f * HID + kheld] = 4.f * __expf(cvheld - M);
  if (tid == 0) cmax[f * DIMF + iRow] = M;
}

// ---------------- main fused kernel: all 5 flows, MFMA (h^T orientation) -----
// 256 blocks x 1024 threads (16 waves). Block owns 16 batch rows; each wave
// owns 4 of the 64 hidden blocks. x persists in LDS across flows.
__global__ __launch_bounds__(1024, 4) void bnaf_main_kernel(
    const float* __restrict__ x_in,
    const float* __restrict__ b1, const float* __restrict__ b2,
    const float* __restrict__ gates,
    const short* __restrict__ wn1s,
    const short* __restrict__ wn2s,
    const float* __restrict__ expc4, const float* __restrict__ cmax,
    float* __restrict__ out)
{
  // LDS map (bytes):
  //   0     .. 4351    xs   fp32 x [16][68]
  //   4352  .. 6527    xb   bf16 B-frags of x (kb-stride 136 shorts)
  //   6528  .. 76159   ts   per-wave bf16 t^T [c16(16)][136 shorts] (4352 B
  //                         each, 16 waves); reused as y-partials (1024 f32)
  //   76160 .. 77183   ldp  [16][16] f32
  __shared__ __attribute__((aligned(16))) char smem[77184];
  float* xs  = (float*)smem;
  short* xbS = (short*)(smem + 4352);
  float* ldp = (float*)(smem + 76160);

  const int tid  = threadIdx.x;
  const int w    = tid >> 6;      // wave 0..15
  const int lane = tid & 63;
  const int c16  = lane & 15;
  const int q    = lane >> 4;
  const int r0   = blockIdx.x * 16;

  short* tsw = (short*)(smem + 6528 + w * 4352);

  {
    int row = tid >> 6, col = tid & 63;
    float v = x_in[((size_t)(r0 + row) << 6) | col];
    xs[row * 68 + col] = v;
    xbS[(col >> 3) * 136 + row * 8 + (col & 7)] = f2bf_s(v);
  }
  float ldtot = 0.f;
  __syncthreads();

  #pragma unroll 1
  for (int f = 0; f < NFLOWS; ++f) {
    const float gatev = (f < NFLOWS - 1) ? gates[f] : 0.f;
    const float spg   = (f < NFLOWS - 1) ? softplus_f(gatev) : 0.f;

    // x B-frags for both k-steps (K=64), shared by all iters of this flow
    const bf16x8 xa0 = *(const bf16x8*)(xbS + q * 136 + c16 * 8);
    const bf16x8 xa1 = *(const bf16x8*)(xbS + (4 + q) * 136 + c16 * 8);

    f32x4 yacc[4];
    #pragma unroll
    for (int n = 0; n < 4; ++n) yacc[n] = f32x4{0.f, 0.f, 0.f, 0.f};
    float ldacc = 0.f;

    #pragma unroll 1
    for (int ii = 0; ii < 4; ++ii) {
      const int i = ii * 16 + w;                 // hidden block (dim index)

      // ---- GEMM1': h^T tile 128x16; wn1 = A operand, x = B operand ----
      const short* p1l = wn1s + (((size_t)(f * 64 + i)) << 13) + lane * 8;
      f32x4 d[8];
      #pragma unroll
      for (int nt = 0; nt < 8; ++nt) {
        bf16x8 bw0 = *(const bf16x8*)(p1l + nt * 1024);
        f32x4 z = {0.f, 0.f, 0.f, 0.f};
        d[nt] = __builtin_amdgcn_mfma_f32_16x16x32_bf16(bw0, xa0, z, 0, 0, 0);
      }
      if (i >= 32) {          // features 32..63 are zero for blocks i < 32
        #pragma unroll
        for (int nt = 0; nt < 8; ++nt) {
          bf16x8 bw1 = *(const bf16x8*)(p1l + nt * 1024 + 512);
          d[nt] = __builtin_amdgcn_mfma_f32_16x16x32_bf16(bw1, xa1, d[nt], 0, 0, 0);
        }
      }

      // ---- elementwise: tanh + lse contributions, t^T -> LDS (b64) ----
      // lane(c16,q), reg r: h[hidden i*128+nt*16+q*4+r][batch c16]
      const float* b1p = b1    + f * HID + i * 128 + q * 4;
      const float* ecp = expc4 + f * HID + i * 128 + q * 4;
      float sacc = 0.f;
      #pragma unroll
      for (int nt = 0; nt < 8; ++nt) {
        float4 b1q = *(const float4*)(b1p + nt * 16);
        float4 ecq = *(const float4*)(ecp + nt * 16);
        float t[4];
        #pragma unroll
        for (int r = 0; r < 4; ++r) {
          float bb = (r == 0) ? b1q.x : (r == 1) ? b1q.y : (r == 2) ? b1q.z : b1q.w;
          float ee = (r == 0) ? ecq.x : (r == 1) ? ecq.y : (r == 2) ? ecq.z : ecq.w;
          float h = d[nt][r] + bb;
          h = fminf(fmaxf(h, -30.f), 30.f);
          float u = __expf(2.f * h);
          float v = __builtin_amdgcn_rcpf(u + 1.f);
          t[r] = fmaf(-2.f, v, 1.f);                 // tanh(h)
          sacc = fmaf(ee * u, v * v, sacc);          // e^{c-M}·(1-t²)
        }
        uint2 pk; pk.x = pk_bf16(t[0], t[1]); pk.y = pk_bf16(t[2], t[3]);
        *(uint2*)(tsw + c16 * 136 + nt * 16 + q * 4) = pk;
      }
      asm volatile("s_waitcnt lgkmcnt(0)" ::: "memory"); // wave-private LDS RAW

      // reduce over q-lanes (hidden split); then grad for this (row, i)
      sacc += __shfl_xor(sacc, 16, 64);
      sacc += __shfl_xor(sacc, 32, 64);
      const float Mi = cmax[f * DIMF + i];
      float grad = Mi + __logf(sacc);
      ldacc += (f < NFLOWS - 1) ? (softplus_f(grad + gatev) - spg) : grad;

      // ---- GEMM2': y^T[64][16] += wn2_slice · t^T; skip all-zero m-tiles ----
      const short* p2l = wn2s + (((size_t)(f * 64 + i)) << 13) + lane * 8;
      const int mt0 = i >> 4;
      #pragma unroll
      for (int ks = 0; ks < 4; ++ks) {
        bf16x8 tb = *(const bf16x8*)(tsw + c16 * 136 + ks * 32 + q * 8);
        #pragma unroll
        for (int mt = 0; mt < 4; ++mt) {
          if (mt >= mt0) {
            bf16x8 wb = *(const bf16x8*)(p2l + (ks * 4 + mt) * 512);
            yacc[mt] = __builtin_amdgcn_mfma_f32_16x16x32_bf16(wb, tb, yacc[mt], 0, 0, 0);
          }
        }
      }
    } // hidden blocks

    // ---- stage per-wave partials (y^T into ts region) ----
    asm volatile("s_waitcnt lgkmcnt(0)" ::: "memory");
    float* ypw = (float*)(smem + 6528 + w * 4352);
    #pragma unroll
    for (int mt = 0; mt < 4; ++mt)
      #pragma unroll
      for (int r = 0; r < 4; ++r)
        ypw[(mt * 4 + r) * 64 + lane] = yacc[mt][r];
    if (q == 0) ldp[w * 16 + c16] = ldacc;
    __syncthreads();

    // ---- epilogue: reduce 16 waves, bias, gate, flip ----
    float sgate = 0.f;
    if (f < NFLOWS - 1) sgate = __builtin_amdgcn_rcpf(1.f + __expf(-gatev));
    int row = tid >> 6, col = tid & 63;
    // y value: out col = mt*16 + q*4 + r, batch = c16 = row
    int idx = (((col >> 4) * 4 + (col & 3)) * 64) + (((col >> 2) & 3) * 16) + row;
    float v = b2[f * DIMF + col];
    #pragma unroll
    for (int ww = 0; ww < 16; ++ww)
      v += ((const float*)(smem + 6528 + ww * 4352))[idx];
    float nx = 0.f; int nrow = 0, ncol = 0;
    if (f < NFLOWS - 1) {
      float xv = xs[row * 68 + col];
      nx = fmaf(sgate, v - xv, xv);        // s*y + (1-s)*x
      nrow = row; ncol = 63 - col;         // flip for next flow
    } else {
      out[((size_t)(r0 + row) << 6) | col] = v;
    }
    if (tid < 16) {
      float a = 0.f;
      #pragma unroll
      for (int ww = 0; ww < 16; ++ww) a += ldp[ww * 16 + tid];
      ldtot += a;
    }
    __syncthreads();
    if (f < NFLOWS - 1) {
      xs[nrow * 68 + ncol] = nx;
      xbS[(ncol >> 3) * 136 + nrow * 8 + (ncol & 7)] = f2bf_s(nx);
      __syncthreads();
    }
  } // flows

  if (tid < 16) out[(size_t)BATCHN * DIMF + r0 + tid] = ldtot;
}

extern "C" void kernel_launch(void* const* d_in, const int* in_sizes, int n_in,
                              void* d_out, int out_size, void* d_ws, size_t ws_size,
                              hipStream_t stream)
{
  const float* x     = (const float*)d_in[0];
  const float* W1    = (const float*)d_in[1];
  const float* d1    = (const float*)d_in[2];
  const float* b1    = (const float*)d_in[3];
  const float* W2    = (const float*)d_in[4];
  const float* d2    = (const float*)d_in[5];
  const float* b2    = (const float*)d_in[6];
  const float* gates = (const float*)d_in[7];
  float* out = (float*)d_out;

  char* ws = (char*)d_ws;
  short* wn1s  = (short*)ws;                                  // 5,242,880 B
  short* wn2s  = (short*)(ws + 5242880);                      // 5,242,880 B
  float* expc4 = (float*)(ws + 10485760);                     //   163,840 B
  float* cmaxp = (float*)(ws + 10649600);                     //     1,280 B
  float* g1    = (float*)(ws + 10650880);                     //   163,840 B

  hipLaunchKernelGGL(prep1_kernel, dim3(10240), dim3(256), 0, stream, W1, d1, wn1s, g1);
  hipLaunchKernelGGL(prep2_kernel, dim3(320), dim3(1024), 0, stream, W2, d2, g1, wn2s, expc4, cmaxp);
  hipLaunchKernelGGL(bnaf_main_kernel, dim3(256), dim3(1024), 0, stream,
                     x, b1, b2, gates, wn1s, wn2s, expc4, cmaxp, out);
}